// Round 10
// baseline (74.590 us; speedup 1.0000x reference)
//
#include <hip/hip_runtime.h>
#include <float.h>

#define BB 32
#define CC 128
#define HH 64
#define WW 64

// Block = 256 thr = 4 waves = 4 channels of one (b, lmi); wave = 1 channel.
// Wave stages its full ROI row-window to LDS via float4 (1KB/instr, 4 KB in
// flight), then bin-max + cell-max from LDS. No __syncthreads anywhere.
// Grid = 32*8*32 = 8192 blocks, b fastest.
__global__ __launch_bounds__(256) void roipool_kernel(
    const float* __restrict__ x,   // [B,C,64,64]
    const float* __restrict__ lm,  // [B,16]
    float* __restrict__ out)       // [B,C,32,16]
{
    int blk = blockIdx.x;
    int b   = blk & 31;
    int lmi = (blk >> 5) & 7;
    int cg  = blk >> 8;          // 0..31

    int wave = threadIdx.x >> 6;
    int lane = threadIdx.x & 63;
    int c = cg * 4 + wave;

    __shared__ float s[4][64][64];    // 64 KB: per-wave full-window staging
    __shared__ float tb[4][8][65];    // 8.3 KB: per-wave bin-max (padded)

    float x0 = lm[b * 16 + 2 * lmi];
    float y0 = lm[b * 16 + 2 * lmi + 1];
    bool visible = (x0 > 0.0f) || (y0 > 0.0f);

    // torchvision column-swap semantics:
    // rois=(b,x1,x2,y1,y2) consumed as (b,start_w,start_h,end_w,end_h)
    int fx = (int)floorf(x0 * 0.25f);
    int fy = (int)floorf(y0 * 0.25f);
    int roi = max(fy - fx + 1, 1);      // roi_w == roi_h
    float bin = (float)roi * 0.125f;    // exact /8

    int i = lane >> 3;   // cell row
    int j = lane & 7;    // cell col
    int orow = 8 * (lmi >> 1) + i;
    int ocol = 8 * (lmi & 1) + j;
    size_t oidx = (((size_t)b * CC + c) * 32 + orow) * 16 + ocol;

    const float* __restrict__ xp = x + (((size_t)b * CC + c) << 12);

    // ---------- fast path: roi==1 -> every cell is pixel (fx, fx-7) ----------
    if (roi == 1) {                     // block-uniform branch
        int hs = min(max(fx, 0), HH),     he = min(max(fx + 1, 0), HH);
        int ws = min(max(fx - 7, 0), WW), we = min(max(fx - 6, 0), WW);
        bool empty = (he <= hs) || (we <= ws) || !visible;
        out[oidx] = empty ? 0.0f : xp[(hs << 6) + ws];
        return;
    }

    int h0 = min(max(fx, 0), HH);
    int h1 = min(max(fx + roi, 0), HH);
    int Hwin = h1 - h0;                 // 0..64

    if (visible && Hwin > 0) {
        // ---- stage 0: window rows -> LDS; lane=(row-in-4, col-quad) ----
        int rl = lane >> 4;             // 0..3
        int cq = (lane & 15) << 2;      // 0,4,...,60
        const float* base = xp + (h0 << 6) + cq;
        int rm = Hwin - 1;
        for (int g = 0; g < Hwin; g += 16) {
            int r0 = g + rl, r1 = r0 + 4, r2 = r0 + 8, r3 = r0 + 12;
            // 4 independent 1KB-contiguous wave-loads in flight (clamped dups ok)
            float4 v0 = *(const float4*)(base + (min(r0, rm) << 6));
            float4 v1 = *(const float4*)(base + (min(r1, rm) << 6));
            float4 v2 = *(const float4*)(base + (min(r2, rm) << 6));
            float4 v3 = *(const float4*)(base + (min(r3, rm) << 6));
            *(float4*)&s[wave][r0][cq] = v0;   // r3 <= 63 always (g<=48)
            *(float4*)&s[wave][r1][cq] = v1;
            *(float4*)&s[wave][r2][cq] = v2;
            *(float4*)&s[wave][r3][cq] = v3;
        }

        // ---- stage 1: per-column max per row-bin, from LDS; lane = column ----
        float bm0, bm1, bm2, bm3, bm4, bm5, bm6, bm7;
        #pragma unroll
        for (int t = 0; t < 8; ++t) {
            int hs = min(max((int)floorf((float)t * bin) + fx, 0), HH);
            int he = min(max((int)ceilf((float)(t + 1) * bin) + fx, 0), HH);
            float acc = -FLT_MAX;
            for (int h = hs; h < he; ++h)
                acc = fmaxf(acc, s[wave][h - h0][lane]);
            if (t == 0) bm0 = acc; else if (t == 1) bm1 = acc;
            else if (t == 2) bm2 = acc; else if (t == 3) bm3 = acc;
            else if (t == 4) bm4 = acc; else if (t == 5) bm5 = acc;
            else if (t == 6) bm6 = acc; else bm7 = acc;
        }
        tb[wave][0][lane] = bm0;  tb[wave][1][lane] = bm1;
        tb[wave][2][lane] = bm2;  tb[wave][3][lane] = bm3;
        tb[wave][4][lane] = bm4;  tb[wave][5][lane] = bm5;
        tb[wave][6][lane] = bm6;  tb[wave][7][lane] = bm7;
    }

    // ---- stage 2: pool columns from tb; thread = (channel, cell i, j) ----
    // Same wave wrote tb -> in-order LDS per wave, no barrier needed.
    int hs = min(max((int)floorf((float)i * bin) + fx, 0), HH);
    int he = min(max((int)ceilf((float)(i + 1) * bin) + fx, 0), HH);
    int ws = min(max((int)floorf((float)j * bin) + fx - 7, 0), WW);
    int we = min(max((int)ceilf((float)(j + 1) * bin) + fx - 7, 0), WW);
    bool empty = (he <= hs) || (we <= ws) || !visible;

    float m = -FLT_MAX;
    if (!empty) {
        for (int w = ws; w < we; ++w)
            m = fmaxf(m, tb[wave][i][w]);
    }
    out[oidx] = empty ? 0.0f : m;
}

extern "C" void kernel_launch(void* const* d_in, const int* in_sizes, int n_in,
                              void* d_out, int out_size, void* d_ws, size_t ws_size,
                              hipStream_t stream) {
    const float* x  = (const float*)d_in[0];
    const float* lm = (const float*)d_in[1];
    float* out = (float*)d_out;

    int blocks = BB * 8 * 32;   // 8192
    roipool_kernel<<<blocks, 256, 0, stream>>>(x, lm, out);
}

// Round 11
// 36.522 us; speedup vs baseline: 2.0423x; 2.0423x over previous
//
#include <hip/hip_runtime.h>
#include <float.h>

#define BB 32
#define CC 128
#define HH 64
#define WW 64
#define NP 2   // consecutive planes (b,c) per block -> 32KB sequential stream

// Block = 256 thr = 4 waves. Block streams NP full 16KB planes into LDS
// sequentially (the WHOLE input is read contiguously at full DRAM BW instead
// of scattered windows at ~1.2 TB/s). Wave w computes landmarks {2w, 2w+1}
// for each plane from LDS. Grid = 32*128/NP = 2048 blocks.
__global__ __launch_bounds__(256) void roipool_kernel(
    const float* __restrict__ x,   // [B,C,64,64]
    const float* __restrict__ lm,  // [B,16]
    float* __restrict__ out)       // [B,C,32,16]
{
    int p0 = blockIdx.x * NP;      // first plane index (b*128+c)
    int b  = p0 >> 7;              // constant within block (NP divides 128)
    int c0 = p0 & 127;

    int tid  = threadIdx.x;
    int wave = tid >> 6;
    int lane = tid & 63;

    __shared__ float s[HH * WW];       // 16 KB: one full plane
    __shared__ float tb[4][8][66];     // 8.4 KB: per-wave bin-max (padded)

    int i = lane >> 3;   // cell row
    int j = lane & 7;    // cell col

    for (int q = 0; q < NP; ++q) {
        int c = c0 + q;
        const float4* __restrict__ plane4 =
            (const float4*)(x + ((size_t)(b * CC + c) << 12));

        // issue the 4KB-per-round sequential loads BEFORE the WAR barrier:
        // global latency overlaps other waves' compute + barrier wait
        float4 v0 = plane4[tid];
        float4 v1 = plane4[tid + 256];
        float4 v2 = plane4[tid + 512];
        float4 v3 = plane4[tid + 768];

        if (q > 0) __syncthreads();    // prev plane's LDS reads done
        ((float4*)s)[tid]       = v0;
        ((float4*)s)[tid + 256] = v1;
        ((float4*)s)[tid + 512] = v2;
        ((float4*)s)[tid + 768] = v3;
        __syncthreads();               // plane visible to all waves

        size_t obase = ((size_t)(b * CC + c)) * (32 * 16);

        #pragma unroll
        for (int k = 0; k < 2; ++k) {
            int lmi = wave * 2 + k;    // wave-uniform landmark
            float x0 = lm[b * 16 + 2 * lmi];
            float y0 = lm[b * 16 + 2 * lmi + 1];
            bool visible = (x0 > 0.0f) || (y0 > 0.0f);

            // torchvision column-swap semantics:
            // rois=(b,x1,x2,y1,y2) consumed as (b,start_w,start_h,end_w,end_h)
            int fx = (int)floorf(x0 * 0.25f);
            int fy = (int)floorf(y0 * 0.25f);
            int roi = max(fy - fx + 1, 1);      // roi_w == roi_h
            float bin = (float)roi * 0.125f;    // exact /8

            int orow = 8 * (lmi >> 1) + i;
            int ocol = 8 * (lmi & 1) + j;
            size_t oidx = obase + (size_t)orow * 16 + ocol;

            if (!visible) { out[oidx] = 0.0f; continue; }   // wave-uniform

            // fast path: roi==1 -> every cell is pixel (fx, fx-7)
            if (roi == 1) {                                  // wave-uniform
                int hs = min(max(fx, 0), HH),     he = min(max(fx + 1, 0), HH);
                int ws = min(max(fx - 7, 0), WW), we = min(max(fx - 6, 0), WW);
                bool empty = (he <= hs) || (we <= ws);
                out[oidx] = empty ? 0.0f : s[(hs << 6) + ws];  // LDS broadcast
                continue;
            }

            // ---- stage 1: per-column max per row-bin, from LDS (lane=col) ----
            #pragma unroll
            for (int t = 0; t < 8; ++t) {
                int hs = min(max((int)floorf((float)t * bin) + fx, 0), HH);
                int he = min(max((int)ceilf((float)(t + 1) * bin) + fx, 0), HH);
                float acc = -FLT_MAX;
                for (int h = hs; h < he; h += 4) {
                    int hm = he - 1;   // clamped dups harmless under max; 4 reads batched
                    float a0 = s[(h << 6) + lane];
                    float a1 = s[(min(h + 1, hm) << 6) + lane];
                    float a2 = s[(min(h + 2, hm) << 6) + lane];
                    float a3 = s[(min(h + 3, hm) << 6) + lane];
                    acc = fmaxf(acc, fmaxf(fmaxf(a0, a1), fmaxf(a2, a3)));
                }
                tb[wave][t][lane] = acc;
            }
            // same wave wrote tb -> in-order LDS, no barrier

            // ---- stage 2: pool bin-max columns; lane = cell (i,j) ----
            int hs = min(max((int)floorf((float)i * bin) + fx, 0), HH);
            int he = min(max((int)ceilf((float)(i + 1) * bin) + fx, 0), HH);
            int ws = min(max((int)floorf((float)j * bin) + fx - 7, 0), WW);
            int we = min(max((int)ceilf((float)(j + 1) * bin) + fx - 7, 0), WW);
            bool empty = (he <= hs) || (we <= ws);

            float m = -FLT_MAX;
            if (!empty) {
                for (int w = ws; w < we; w += 4) {
                    int wm = we - 1;
                    float b0 = tb[wave][i][w];
                    float b1 = tb[wave][i][min(w + 1, wm)];
                    float b2 = tb[wave][i][min(w + 2, wm)];
                    float b3 = tb[wave][i][min(w + 3, wm)];
                    m = fmaxf(m, fmaxf(fmaxf(b0, b1), fmaxf(b2, b3)));
                }
            }
            out[oidx] = empty ? 0.0f : m;
        }
    }
}

extern "C" void kernel_launch(void* const* d_in, const int* in_sizes, int n_in,
                              void* d_out, int out_size, void* d_ws, size_t ws_size,
                              hipStream_t stream) {
    const float* x  = (const float*)d_in[0];
    const float* lm = (const float*)d_in[1];
    float* out = (float*)d_out;

    int blocks = BB * CC / NP;   // 2048
    roipool_kernel<<<blocks, 256, 0, stream>>>(x, lm, out);
}